// Round 3
// baseline (13594.264 us; speedup 1.0000x reference)
//
#include <hip/hip_runtime.h>
#include <hip/hip_bf16.h>
#include <hip/hip_fp16.h>

typedef _Float16 f16;
typedef __attribute__((ext_vector_type(8))) _Float16 f16x8;
typedef __attribute__((ext_vector_type(4))) float f32x4;

__device__ __forceinline__ float sigmoidf_(float x) { return 1.0f / (1.0f + __expf(-x)); }
__device__ __forceinline__ float tanhf_(float x) { return 2.0f / (1.0f + __expf(-2.0f * x)) - 1.0f; }

// in: R x C fp32 row-major -> out: C x R f16 row-major (i.e. transposed)
__global__ __launch_bounds__(256) void k_transpose_cvt(const float* __restrict__ in, f16* __restrict__ out, int R, int C) {
    int idx = blockIdx.x * 256 + threadIdx.x;
    if (idx < R * C) {
        int r = idx / C;
        int c = idx - r * C;
        out[(long)c * R + r] = (f16)in[idx];
    }
}

// Build weight frag-stream: for js slice (16 units), wave w (K-quarter), frag (mat, kk, nt=gate):
// chunk id = (((js*2+mat)*64 + w*16+kk*4+nt)*64 + lane), holds the f16x8 B-frag for that lane.
__global__ __launch_bounds__(256) void k_wfs(const f16* __restrict__ WiT, const f16* __restrict__ WhT,
                                             f16* __restrict__ Wfs) {
    int id = blockIdx.x * 256 + threadIdx.x;      // 262144 chunks
    int lane = id & 63;
    int f    = (id >> 6) & 63;                    // w*16 + kk*4 + nt
    int mat  = (id >> 12) & 1;
    int js   = id >> 13;                          // 0..31
    int nt = f & 3, kk = (f >> 2) & 3, w = f >> 4;
    const f16* WT = mat ? WhT : WiT;              // [2048][512] row-major (W^T)
    int col = nt * 512 + js * 16 + (lane & 15);   // gate nt, unit js*16 + l15
    int k   = (w * 4 + kk) * 32 + (lane >> 4) * 8;
    *(f16x8*)(Wfs + (long)id * 8) = *(const f16x8*)(WT + (long)col * 512 + k);
}

// ---------------- GEMM: C(MxN) = act(A(MxK) * BT(NxK)^T + bias), encoder use ----------------
template <int DO_GELU, int A_FP32>
__global__ __launch_bounds__(256) void k_gemm_bt(
    const void* __restrict__ Av, const f16* __restrict__ BT, const float* __restrict__ bias,
    f16* __restrict__ C, int M, int N, int K)
{
    __shared__ f16 As[128 * 32];
    __shared__ f16 Bs[128 * 32];
    const int tid = threadIdx.x;
    const int lane = tid & 63;
    const int wave = tid >> 6;
    const long m0 = (long)blockIdx.x * 128;
    const long n0 = (long)blockIdx.y * 128;
    const int wm = (wave >> 1) * 64, wn = (wave & 1) * 64;
    const int l15 = lane & 15, lq = lane >> 4;

    f32x4 acc[4][4] = {};

    for (int k0 = 0; k0 < K; k0 += 32) {
        __syncthreads();
#pragma unroll
        for (int i = 0; i < 2; i++) {
            int v = tid + 256 * i;
            int row = v >> 2, part = v & 3;
            if (A_FP32) {
                const float* A32 = (const float*)Av;
                const float* p = A32 + (m0 + row) * (long)K + k0 + part * 8;
                float4 v0 = *(const float4*)p;
                float4 v1 = *(const float4*)(p + 4);
                f16x8 o;
                o[0] = (f16)v0.x; o[1] = (f16)v0.y; o[2] = (f16)v0.z; o[3] = (f16)v0.w;
                o[4] = (f16)v1.x; o[5] = (f16)v1.y; o[6] = (f16)v1.z; o[7] = (f16)v1.w;
                *(f16x8*)&As[row * 32 + part * 8] = o;
            } else {
                const f16* A16 = (const f16*)Av;
                *(f16x8*)&As[row * 32 + part * 8] = *(const f16x8*)(A16 + (m0 + row) * (long)K + k0 + part * 8);
            }
            *(f16x8*)&Bs[row * 32 + part * 8] = *(const f16x8*)(BT + (n0 + row) * (long)K + k0 + part * 8);
        }
        __syncthreads();
        f16x8 af[4], bf[4];
#pragma unroll
        for (int i = 0; i < 4; i++) af[i] = *(const f16x8*)&As[(wm + i * 16 + l15) * 32 + lq * 8];
#pragma unroll
        for (int j = 0; j < 4; j++) bf[j] = *(const f16x8*)&Bs[(wn + j * 16 + l15) * 32 + lq * 8];
#pragma unroll
        for (int i = 0; i < 4; i++)
#pragma unroll
            for (int j = 0; j < 4; j++)
                acc[i][j] = __builtin_amdgcn_mfma_f32_16x16x32_f16(af[i], bf[j], acc[i][j], 0, 0, 0);
    }

#pragma unroll
    for (int i = 0; i < 4; i++) {
#pragma unroll
        for (int j = 0; j < 4; j++) {
#pragma unroll
            for (int r = 0; r < 4; r++) {
                long row = m0 + wm + i * 16 + lq * 4 + r;
                long col = n0 + wn + j * 16 + l15;
                float v = acc[i][j][r] + bias[col];
                if (DO_GELU) {
                    float u = 0.7978845608028654f * (v + 0.044715f * v * v * v);
                    v = 0.5f * v * (1.0f + tanhf(u));
                }
                C[row * (long)N + col] = (f16)v;
            }
        }
    }
}

// ---------------- persistent LSTM scan (64 steps per launch) ----------------
// grid 256 = bg(8: 32 batch rows) x js(32: 16 hidden units). Cluster = 32 blocks sharing bg,
// lockstepped by per-(t,bg) atomic counters. Waves split K (zero A redundancy); W_i/W_h frags
// live in VGPRs (loaded from frag-stream Wfs). z partials combined in LDS zbuf.
__global__ __launch_bounds__(256) void k_scan(
    const f16* __restrict__ Wfs, const f16* __restrict__ feats,  // feats: chunk [64][256][512]
    f16* __restrict__ ys, float* __restrict__ cbuf,
    const float* __restrict__ b_lstm, int* __restrict__ ctr, int t0)
{
    __shared__ float zbuf[4][32][68];   // [wave][row b][col g*16+u], pad 68 for bank spread
    const int tid = threadIdx.x;
    const int lane = tid & 63, w = tid >> 6;
    const int l15 = lane & 15, lq = lane >> 4;
    const int js = blockIdx.x & 31, bg = blockIdx.x >> 5;
    const int B0 = bg * 32, j0 = js * 16;

    // weight fragments -> registers (128 VGPRs): [mat][kk][nt]
    f16x8 wfrag[2][4][4];
#pragma unroll
    for (int mat = 0; mat < 2; mat++)
#pragma unroll
        for (int kk = 0; kk < 4; kk++)
#pragma unroll
            for (int nt = 0; nt < 4; nt++)
                wfrag[mat][kk][nt] = *(const f16x8*)(Wfs +
                    ((long)((js * 2 + mat) * 64 + w * 16 + kk * 4 + nt) * 64 + lane) * 8);

    const int jj = tid & 15;
    const int b1 = tid >> 4, b2 = b1 + 16;
    float bias_v[4];
#pragma unroll
    for (int g = 0; g < 4; g++) bias_v[g] = b_lstm[g * 512 + j0 + jj];

    float c1, c2;
    if (t0 == 0) { c1 = 0.0f; c2 = 0.0f; }
    else {
        c1 = cbuf[(long)(B0 + b1) * 512 + j0 + jj];
        c2 = cbuf[(long)(B0 + b2) * 512 + j0 + jj];
    }

    for (int t = t0; t < t0 + 64; t++) {
        f32x4 acc[2][4] = {};

        // x-projection: independent of the barrier -> overlaps cluster stragglers
        const f16* fA = feats + ((long)(t - t0) * 256 + B0) * 512 + w * 128 + lq * 8;
#pragma unroll
        for (int kk = 0; kk < 4; kk++) {
            f16x8 xa0 = *(const f16x8*)(fA + (long)l15 * 512 + kk * 32);
            f16x8 xa1 = *(const f16x8*)(fA + (long)(16 + l15) * 512 + kk * 32);
#pragma unroll
            for (int nt = 0; nt < 4; nt++) {
                acc[0][nt] = __builtin_amdgcn_mfma_f32_16x16x32_f16(xa0, wfrag[0][kk][nt], acc[0][nt], 0, 0, 0);
                acc[1][nt] = __builtin_amdgcn_mfma_f32_16x16x32_f16(xa1, wfrag[0][kk][nt], acc[1][nt], 0, 0, 0);
            }
        }

        // wait for h(t-1) from the 32-block cluster (launch boundary covers t==t0)
        if (tid == 0 && t > t0) {
            while (__hip_atomic_load(&ctr[(t - 1) * 8 + bg], __ATOMIC_ACQUIRE, __HIP_MEMORY_SCOPE_AGENT) < 32) {}
            __threadfence();
        }
        __syncthreads();

        if (t > 0) {
            const f16* hA = ys + ((long)(t - 1) * 256 + B0) * 512 + w * 128 + lq * 8;
#pragma unroll
            for (int kk = 0; kk < 4; kk++) {
                f16x8 ha0 = *(const f16x8*)(hA + (long)l15 * 512 + kk * 32);
                f16x8 ha1 = *(const f16x8*)(hA + (long)(16 + l15) * 512 + kk * 32);
#pragma unroll
                for (int nt = 0; nt < 4; nt++) {
                    acc[0][nt] = __builtin_amdgcn_mfma_f32_16x16x32_f16(ha0, wfrag[1][kk][nt], acc[0][nt], 0, 0, 0);
                    acc[1][nt] = __builtin_amdgcn_mfma_f32_16x16x32_f16(ha1, wfrag[1][kk][nt], acc[1][nt], 0, 0, 0);
                }
            }
        }

        // K-partials -> LDS (C/D layout: col=lane&15, row=lq*4+r)
#pragma unroll
        for (int mt = 0; mt < 2; mt++)
#pragma unroll
            for (int nt = 0; nt < 4; nt++)
#pragma unroll
                for (int r = 0; r < 4; r++)
                    zbuf[w][mt * 16 + lq * 4 + r][nt * 16 + l15] = acc[mt][nt][r];
        __syncthreads();

        // gate phase: each thread owns (b1,jj) and (b2,jj)
        {
            float zs1[4], zs2[4];
#pragma unroll
            for (int g = 0; g < 4; g++) {
                float a1 = bias_v[g], a2 = bias_v[g];
#pragma unroll
                for (int ww = 0; ww < 4; ww++) {
                    a1 += zbuf[ww][b1][g * 16 + jj];
                    a2 += zbuf[ww][b2][g * 16 + jj];
                }
                zs1[g] = a1; zs2[g] = a2;
            }
            c1 = sigmoidf_(zs1[1]) * c1 + sigmoidf_(zs1[0]) * tanhf_(zs1[2]);
            float h1 = sigmoidf_(zs1[3]) * tanhf_(c1);
            c2 = sigmoidf_(zs2[1]) * c2 + sigmoidf_(zs2[0]) * tanhf_(zs2[2]);
            float h2 = sigmoidf_(zs2[3]) * tanhf_(c2);
            ys[(long)t * 131072 + (long)(B0 + b1) * 512 + j0 + jj] = (f16)h1;
            ys[(long)t * 131072 + (long)(B0 + b2) * 512 + j0 + jj] = (f16)h2;
        }
        __syncthreads();   // h stores drained (vmcnt) + zbuf reads done before reuse

        if (tid == 0) {
            __threadfence();  // push block's h(t) to device scope (wbl2)
            __hip_atomic_fetch_add(&ctr[t * 8 + bg], 1, __ATOMIC_RELEASE, __HIP_MEMORY_SCOPE_AGENT);
        }
    }

    cbuf[(long)(B0 + b1) * 512 + j0 + jj] = c1;
    cbuf[(long)(B0 + b2) * 512 + j0 + jj] = c2;
}

// ---------------- heads: mu, sigma, value (unchanged from round 2) ----------------
__global__ __launch_bounds__(256) void k_heads(
    const f16* __restrict__ ys, const float* __restrict__ Wmu, const float* __restrict__ bmu,
    const float* __restrict__ logstd, const float* __restrict__ Wv, const float* __restrict__ bv,
    float* __restrict__ mu, float* __restrict__ sigma, float* __restrict__ value)
{
    __shared__ f16 hsm[8][512];
    const int tid = threadIdx.x;
    const long base_row = (long)blockIdx.x * 8;
    for (int v = tid; v < 512; v += 256) {
        int row = v >> 6, part = v & 63;
        *(f16x8*)&hsm[row][part * 8] = *(const f16x8*)(ys + (base_row + row) * 512 + part * 8);
    }
    __syncthreads();
    const int n = tid & 31, rl = tid >> 5;
    float accm = 0.0f, accv = 0.0f;
    for (int k = 0; k < 512; k++) accm += (float)hsm[rl][k] * Wmu[k * 32 + n];
    for (int kk = 0; kk < 16; kk++) {
        int k = n + kk * 32;
        accv += (float)hsm[rl][k] * Wv[k];
    }
    for (int off = 16; off; off >>= 1) accv += __shfl_down(accv, off, 32);
    long r = base_row + rl;
    mu[r * 32 + n] = accm + bmu[n];
    sigma[r * 32 + n] = expf(logstd[n]);
    if (n == 0) value[r] = accv + bv[0];
}

// ---------------- launcher ----------------
// ws layout (bytes):
//   ys     @ 0          134217728  (131072 x 512 f16)
//   fchunk @ 134217728  16777216   (16384 x 512 f16)
//   WiT    @ 150994944  2097152
//   WhT    @ 153092096  2097152
//   WencT  @ 155189248  262144
//   Wfs    @ 155451392  4194304    (frag-stream Wi+Wh)
//   cbuf   @ 159645696  524288     (256 x 512 f32)
//   ctr    @ 160169984  16384      (512 x 8 int)
//   total ~160.2 MB (known-good <= 213 MB)

extern "C" void kernel_launch(void* const* d_in, const int* in_sizes, int n_in,
                              void* d_out, int out_size, void* d_ws, size_t ws_size,
                              hipStream_t stream)
{
    const float* x      = (const float*)d_in[0];
    const float* W_enc  = (const float*)d_in[1];
    const float* b_enc  = (const float*)d_in[2];
    const float* W_i    = (const float*)d_in[3];
    const float* W_h    = (const float*)d_in[4];
    const float* b_lstm = (const float*)d_in[5];
    const float* W_mu   = (const float*)d_in[6];
    const float* b_mu   = (const float*)d_in[7];
    const float* log_std= (const float*)d_in[8];
    const float* W_v    = (const float*)d_in[9];
    const float* b_v    = (const float*)d_in[10];

    char* ws = (char*)d_ws;
    f16*   ys    = (f16*)(ws);
    f16*   fchunk= (f16*)(ws + 134217728);
    f16*   WiT   = (f16*)(ws + 150994944);
    f16*   WhT   = (f16*)(ws + 153092096);
    f16*   WencT = (f16*)(ws + 155189248);
    f16*   Wfs   = (f16*)(ws + 155451392);
    float* cbuf  = (float*)(ws + 159645696);
    int*   ctr   = (int*)(ws + 160169984);

    float* mu    = (float*)d_out;
    float* sigma = mu + 4194304;
    float* value = mu + 8388608;

    hipMemsetAsync(ctr, 0, 512 * 8 * sizeof(int), stream);
    hipLaunchKernelGGL(k_transpose_cvt, dim3(512), dim3(256), 0, stream, W_enc, WencT, 256, 512);
    hipLaunchKernelGGL(k_transpose_cvt, dim3(4096), dim3(256), 0, stream, W_i, WiT, 512, 2048);
    hipLaunchKernelGGL(k_transpose_cvt, dim3(4096), dim3(256), 0, stream, W_h, WhT, 512, 2048);
    hipLaunchKernelGGL(k_wfs, dim3(1024), dim3(256), 0, stream, WiT, WhT, Wfs);

    for (int t0 = 0; t0 < 512; t0 += 64) {
        // feats_chunk = gelu(x[t0:t0+64] @ W_enc + b_enc): M=16384, N=512, K=256 (A fp32)
        hipLaunchKernelGGL((k_gemm_bt<1, 1>), dim3(128, 4), dim3(256), 0, stream,
                           (const void*)(x + (long)t0 * 256 * 256), WencT, b_enc, fchunk,
                           16384, 512, 256);
        const f16* wfs_c = Wfs; const f16* f_c = fchunk;
        void* args[] = { (void*)&wfs_c, (void*)&f_c, (void*)&ys, (void*)&cbuf,
                         (void*)&b_lstm, (void*)&ctr, (void*)&t0 };
        hipLaunchCooperativeKernel((const void*)k_scan, dim3(256), dim3(256), args, 0, stream);
    }

    hipLaunchKernelGGL(k_heads, dim3(16384), dim3(256), 0, stream,
                       ys, W_mu, b_mu, log_std, W_v, b_v, mu, sigma, value);
}

// Round 4
// 6058.810 us; speedup vs baseline: 2.2437x; 2.2437x over previous
//
#include <hip/hip_runtime.h>
#include <hip/hip_bf16.h>
#include <hip/hip_fp16.h>

typedef _Float16 f16;
typedef __attribute__((ext_vector_type(8))) _Float16 f16x8;
typedef __attribute__((ext_vector_type(4))) float f32x4;

__device__ __forceinline__ float sigmoidf_(float x) { return 1.0f / (1.0f + __expf(-x)); }
__device__ __forceinline__ float tanhf_(float x) { return 2.0f / (1.0f + __expf(-2.0f * x)) - 1.0f; }

// in: R x C fp32 row-major -> out: C x R f16 row-major (i.e. transposed)
__global__ __launch_bounds__(256) void k_transpose_cvt(const float* __restrict__ in, f16* __restrict__ out, int R, int C) {
    int idx = blockIdx.x * 256 + threadIdx.x;
    if (idx < R * C) {
        int r = idx / C;
        int c = idx - r * C;
        out[(long)c * R + r] = (f16)in[idx];
    }
}

// Build weight frag-stream: for js slice (16 units), wave w (K-quarter), frag (mat, kk, nt=gate):
// chunk id = (((js*2+mat)*64 + w*16+kk*4+nt)*64 + lane), holds the f16x8 B-frag for that lane.
__global__ __launch_bounds__(256) void k_wfs(const f16* __restrict__ WiT, const f16* __restrict__ WhT,
                                             f16* __restrict__ Wfs) {
    int id = blockIdx.x * 256 + threadIdx.x;      // 262144 chunks
    int lane = id & 63;
    int f    = (id >> 6) & 63;                    // w*16 + kk*4 + nt
    int mat  = (id >> 12) & 1;
    int js   = id >> 13;                          // 0..31
    int nt = f & 3, kk = (f >> 2) & 3, w = f >> 4;
    const f16* WT = mat ? WhT : WiT;              // [2048][512] row-major (W^T)
    int col = nt * 512 + js * 16 + (lane & 15);   // gate nt, unit js*16 + l15
    int k   = (w * 4 + kk) * 32 + (lane >> 4) * 8;
    *(f16x8*)(Wfs + (long)id * 8) = *(const f16x8*)(WT + (long)col * 512 + k);
}

// ---------------- GEMM: C(MxN) = act(A(MxK) * BT(NxK)^T + bias), encoder use ----------------
template <int DO_GELU, int A_FP32>
__global__ __launch_bounds__(256) void k_gemm_bt(
    const void* __restrict__ Av, const f16* __restrict__ BT, const float* __restrict__ bias,
    f16* __restrict__ C, int M, int N, int K)
{
    __shared__ f16 As[128 * 32];
    __shared__ f16 Bs[128 * 32];
    const int tid = threadIdx.x;
    const int lane = tid & 63;
    const int wave = tid >> 6;
    const long m0 = (long)blockIdx.x * 128;
    const long n0 = (long)blockIdx.y * 128;
    const int wm = (wave >> 1) * 64, wn = (wave & 1) * 64;
    const int l15 = lane & 15, lq = lane >> 4;

    f32x4 acc[4][4] = {};

    for (int k0 = 0; k0 < K; k0 += 32) {
        __syncthreads();
#pragma unroll
        for (int i = 0; i < 2; i++) {
            int v = tid + 256 * i;
            int row = v >> 2, part = v & 3;
            if (A_FP32) {
                const float* A32 = (const float*)Av;
                const float* p = A32 + (m0 + row) * (long)K + k0 + part * 8;
                float4 v0 = *(const float4*)p;
                float4 v1 = *(const float4*)(p + 4);
                f16x8 o;
                o[0] = (f16)v0.x; o[1] = (f16)v0.y; o[2] = (f16)v0.z; o[3] = (f16)v0.w;
                o[4] = (f16)v1.x; o[5] = (f16)v1.y; o[6] = (f16)v1.z; o[7] = (f16)v1.w;
                *(f16x8*)&As[row * 32 + part * 8] = o;
            } else {
                const f16* A16 = (const f16*)Av;
                *(f16x8*)&As[row * 32 + part * 8] = *(const f16x8*)(A16 + (m0 + row) * (long)K + k0 + part * 8);
            }
            *(f16x8*)&Bs[row * 32 + part * 8] = *(const f16x8*)(BT + (n0 + row) * (long)K + k0 + part * 8);
        }
        __syncthreads();
        f16x8 af[4], bf[4];
#pragma unroll
        for (int i = 0; i < 4; i++) af[i] = *(const f16x8*)&As[(wm + i * 16 + l15) * 32 + lq * 8];
#pragma unroll
        for (int j = 0; j < 4; j++) bf[j] = *(const f16x8*)&Bs[(wn + j * 16 + l15) * 32 + lq * 8];
#pragma unroll
        for (int i = 0; i < 4; i++)
#pragma unroll
            for (int j = 0; j < 4; j++)
                acc[i][j] = __builtin_amdgcn_mfma_f32_16x16x32_f16(af[i], bf[j], acc[i][j], 0, 0, 0);
    }

#pragma unroll
    for (int i = 0; i < 4; i++) {
#pragma unroll
        for (int j = 0; j < 4; j++) {
#pragma unroll
            for (int r = 0; r < 4; r++) {
                long row = m0 + wm + i * 16 + lq * 4 + r;
                long col = n0 + wn + j * 16 + l15;
                float v = acc[i][j][r] + bias[col];
                if (DO_GELU) {
                    float u = 0.7978845608028654f * (v + 0.044715f * v * v * v);
                    v = 0.5f * v * (1.0f + tanhf(u));
                }
                C[row * (long)N + col] = (f16)v;
            }
        }
    }
}

// ---------------- persistent LSTM scan (64 steps per launch) ----------------
// grid 256 = js(32: 16 hidden units) x bg(8: 32 batch rows), bg = blockIdx & 7 so the 32
// blocks of one cluster land on one XCD under round-robin dispatch (perf heuristic only;
// correctness carried by agent-scope release/acquire). Spin uses RELAXED polls + ONE
// acquire on exit (round-3 bug: acquire-per-poll = invalidation storm, 134 MB HBM refetch).
__global__ __launch_bounds__(256, 1) void k_scan(
    const f16* __restrict__ Wfs, const f16* __restrict__ feats,  // feats: chunk [64][256][512]
    f16* __restrict__ ys, float* __restrict__ cbuf,
    const float* __restrict__ b_lstm, int* __restrict__ ctr, int t0)
{
    __shared__ float zbuf[4][32][68];   // [wave][row b][col g*16+u]
    const int tid = threadIdx.x;
    const int lane = tid & 63, w = tid >> 6;
    const int l15 = lane & 15, lq = lane >> 4;
    const int bg = blockIdx.x & 7, js = blockIdx.x >> 3;
    const int B0 = bg * 32, j0 = js * 16;

    // weight fragments -> registers (128 regs): [mat][kk][nt]
    f16x8 wfrag[2][4][4];
#pragma unroll
    for (int mat = 0; mat < 2; mat++)
#pragma unroll
        for (int kk = 0; kk < 4; kk++)
#pragma unroll
            for (int nt = 0; nt < 4; nt++)
                wfrag[mat][kk][nt] = *(const f16x8*)(Wfs +
                    ((long)((js * 2 + mat) * 64 + w * 16 + kk * 4 + nt) * 64 + lane) * 8);

    const int jj = tid & 15;
    const int b1 = tid >> 4, b2 = b1 + 16;
    float bias_v[4];
#pragma unroll
    for (int g = 0; g < 4; g++) bias_v[g] = b_lstm[g * 512 + j0 + jj];

    float c1, c2;
    if (t0 == 0) { c1 = 0.0f; c2 = 0.0f; }
    else {
        c1 = cbuf[(long)(B0 + b1) * 512 + j0 + jj];
        c2 = cbuf[(long)(B0 + b2) * 512 + j0 + jj];
    }

    for (int t = t0; t < t0 + 64; t++) {
        f32x4 acc[2][4] = {};

        // x-projection: independent of the barrier -> overlaps cluster stragglers
        const f16* fA = feats + ((long)(t - t0) * 256 + B0) * 512 + w * 128 + lq * 8;
#pragma unroll
        for (int kk = 0; kk < 4; kk++) {
            f16x8 xa0 = *(const f16x8*)(fA + (long)l15 * 512 + kk * 32);
            f16x8 xa1 = *(const f16x8*)(fA + (long)(16 + l15) * 512 + kk * 32);
#pragma unroll
            for (int nt = 0; nt < 4; nt++) {
                acc[0][nt] = __builtin_amdgcn_mfma_f32_16x16x32_f16(xa0, wfrag[0][kk][nt], acc[0][nt], 0, 0, 0);
                acc[1][nt] = __builtin_amdgcn_mfma_f32_16x16x32_f16(xa1, wfrag[0][kk][nt], acc[1][nt], 0, 0, 0);
            }
        }

        // wait for h(t-1) from the 32-block cluster (launch boundary covers t==t0)
        if (tid == 0 && t > t0) {
            const int ci = ((t - 1) * 8 + bg) * 16;   // 64B-padded counter
            while (__hip_atomic_load(&ctr[ci], __ATOMIC_RELAXED, __HIP_MEMORY_SCOPE_AGENT) < 32)
                __builtin_amdgcn_s_sleep(1);
            (void)__hip_atomic_load(&ctr[ci], __ATOMIC_ACQUIRE, __HIP_MEMORY_SCOPE_AGENT);
        }
        __syncthreads();

        if (t > 0) {
            const f16* hA = ys + ((long)(t - 1) * 256 + B0) * 512 + w * 128 + lq * 8;
#pragma unroll
            for (int kk = 0; kk < 4; kk++) {
                f16x8 ha0 = *(const f16x8*)(hA + (long)l15 * 512 + kk * 32);
                f16x8 ha1 = *(const f16x8*)(hA + (long)(16 + l15) * 512 + kk * 32);
#pragma unroll
                for (int nt = 0; nt < 4; nt++) {
                    acc[0][nt] = __builtin_amdgcn_mfma_f32_16x16x32_f16(ha0, wfrag[1][kk][nt], acc[0][nt], 0, 0, 0);
                    acc[1][nt] = __builtin_amdgcn_mfma_f32_16x16x32_f16(ha1, wfrag[1][kk][nt], acc[1][nt], 0, 0, 0);
                }
            }
        }

        // K-partials -> LDS (C/D layout: col=lane&15, row=lq*4+r)
#pragma unroll
        for (int mt = 0; mt < 2; mt++)
#pragma unroll
            for (int nt = 0; nt < 4; nt++)
#pragma unroll
                for (int r = 0; r < 4; r++)
                    zbuf[w][mt * 16 + lq * 4 + r][nt * 16 + l15] = acc[mt][nt][r];
        __syncthreads();

        // gate phase: each thread owns (b1,jj) and (b2,jj)
        {
            float zs1[4], zs2[4];
#pragma unroll
            for (int g = 0; g < 4; g++) {
                float a1 = bias_v[g], a2 = bias_v[g];
#pragma unroll
                for (int ww = 0; ww < 4; ww++) {
                    a1 += zbuf[ww][b1][g * 16 + jj];
                    a2 += zbuf[ww][b2][g * 16 + jj];
                }
                zs1[g] = a1; zs2[g] = a2;
            }
            c1 = sigmoidf_(zs1[1]) * c1 + sigmoidf_(zs1[0]) * tanhf_(zs1[2]);
            float h1 = sigmoidf_(zs1[3]) * tanhf_(c1);
            c2 = sigmoidf_(zs2[1]) * c2 + sigmoidf_(zs2[0]) * tanhf_(zs2[2]);
            float h2 = sigmoidf_(zs2[3]) * tanhf_(c2);
            ys[(long)t * 131072 + (long)(B0 + b1) * 512 + j0 + jj] = (f16)h1;
            ys[(long)t * 131072 + (long)(B0 + b2) * 512 + j0 + jj] = (f16)h2;
        }
        __syncthreads();   // h stores drained (vmcnt) + zbuf reads done before reuse

        if (tid == 0) {
            // RELEASE add publishes this block's h(t) (carries the needed cache ops)
            __hip_atomic_fetch_add(&ctr[(t * 8 + bg) * 16], 1, __ATOMIC_RELEASE, __HIP_MEMORY_SCOPE_AGENT);
        }
    }

    cbuf[(long)(B0 + b1) * 512 + j0 + jj] = c1;
    cbuf[(long)(B0 + b2) * 512 + j0 + jj] = c2;
}

// ---------------- heads: mu, sigma, value ----------------
__global__ __launch_bounds__(256) void k_heads(
    const f16* __restrict__ ys, const float* __restrict__ Wmu, const float* __restrict__ bmu,
    const float* __restrict__ logstd, const float* __restrict__ Wv, const float* __restrict__ bv,
    float* __restrict__ mu, float* __restrict__ sigma, float* __restrict__ value)
{
    __shared__ f16 hsm[8][512];
    const int tid = threadIdx.x;
    const long base_row = (long)blockIdx.x * 8;
    for (int v = tid; v < 512; v += 256) {
        int row = v >> 6, part = v & 63;
        *(f16x8*)&hsm[row][part * 8] = *(const f16x8*)(ys + (base_row + row) * 512 + part * 8);
    }
    __syncthreads();
    const int n = tid & 31, rl = tid >> 5;
    float accm = 0.0f, accv = 0.0f;
    for (int k = 0; k < 512; k++) accm += (float)hsm[rl][k] * Wmu[k * 32 + n];
    for (int kk = 0; kk < 16; kk++) {
        int k = n + kk * 32;
        accv += (float)hsm[rl][k] * Wv[k];
    }
    for (int off = 16; off; off >>= 1) accv += __shfl_down(accv, off, 32);
    long r = base_row + rl;
    mu[r * 32 + n] = accm + bmu[n];
    sigma[r * 32 + n] = expf(logstd[n]);
    if (n == 0) value[r] = accv + bv[0];
}

// ---------------- launcher ----------------
// ws layout (bytes):
//   ys     @ 0          134217728  (131072 x 512 f16)
//   fchunk @ 134217728  16777216   (16384 x 512 f16)
//   WiT    @ 150994944  2097152
//   WhT    @ 153092096  2097152
//   WencT  @ 155189248  262144
//   Wfs    @ 155451392  4194304    (frag-stream Wi+Wh)
//   cbuf   @ 159645696  524288     (256 x 512 f32)
//   ctr    @ 160169984  262144     (512 x 8 counters, 64B padded)
//   total ~160.4 MB (known-good <= 213 MB)

extern "C" void kernel_launch(void* const* d_in, const int* in_sizes, int n_in,
                              void* d_out, int out_size, void* d_ws, size_t ws_size,
                              hipStream_t stream)
{
    const float* x      = (const float*)d_in[0];
    const float* W_enc  = (const float*)d_in[1];
    const float* b_enc  = (const float*)d_in[2];
    const float* W_i    = (const float*)d_in[3];
    const float* W_h    = (const float*)d_in[4];
    const float* b_lstm = (const float*)d_in[5];
    const float* W_mu   = (const float*)d_in[6];
    const float* b_mu   = (const float*)d_in[7];
    const float* log_std= (const float*)d_in[8];
    const float* W_v    = (const float*)d_in[9];
    const float* b_v    = (const float*)d_in[10];

    char* ws = (char*)d_ws;
    f16*   ys    = (f16*)(ws);
    f16*   fchunk= (f16*)(ws + 134217728);
    f16*   WiT   = (f16*)(ws + 150994944);
    f16*   WhT   = (f16*)(ws + 153092096);
    f16*   WencT = (f16*)(ws + 155189248);
    f16*   Wfs   = (f16*)(ws + 155451392);
    float* cbuf  = (float*)(ws + 159645696);
    int*   ctr   = (int*)(ws + 160169984);

    float* mu    = (float*)d_out;
    float* sigma = mu + 4194304;
    float* value = mu + 8388608;

    hipMemsetAsync(ctr, 0, 262144, stream);
    hipLaunchKernelGGL(k_transpose_cvt, dim3(512), dim3(256), 0, stream, W_enc, WencT, 256, 512);
    hipLaunchKernelGGL(k_transpose_cvt, dim3(4096), dim3(256), 0, stream, W_i, WiT, 512, 2048);
    hipLaunchKernelGGL(k_transpose_cvt, dim3(4096), dim3(256), 0, stream, W_h, WhT, 512, 2048);
    hipLaunchKernelGGL(k_wfs, dim3(1024), dim3(256), 0, stream, WiT, WhT, Wfs);

    for (int t0 = 0; t0 < 512; t0 += 64) {
        // feats_chunk = gelu(x[t0:t0+64] @ W_enc + b_enc): M=16384, N=512, K=256 (A fp32)
        hipLaunchKernelGGL((k_gemm_bt<1, 1>), dim3(128, 4), dim3(256), 0, stream,
                           (const void*)(x + (long)t0 * 256 * 256), WencT, b_enc, fchunk,
                           16384, 512, 256);
        const f16* wfs_c = Wfs; const f16* f_c = fchunk;
        void* args[] = { (void*)&wfs_c, (void*)&f_c, (void*)&ys, (void*)&cbuf,
                         (void*)&b_lstm, (void*)&ctr, (void*)&t0 };
        hipLaunchCooperativeKernel((const void*)k_scan, dim3(256), dim3(256), args, 0, stream);
    }

    hipLaunchKernelGGL(k_heads, dim3(16384), dim3(256), 0, stream,
                       ys, W_mu, b_mu, log_std, W_v, b_v, mu, sigma, value);
}

// Round 6
// 3491.413 us; speedup vs baseline: 3.8936x; 1.7353x over previous
//
#include <hip/hip_runtime.h>
#include <hip/hip_bf16.h>
#include <hip/hip_fp16.h>

typedef _Float16 f16;
typedef __attribute__((ext_vector_type(8))) _Float16 f16x8;
typedef __attribute__((ext_vector_type(4))) float f32x4;

__device__ __forceinline__ float sigmoidf_(float x) { return 1.0f / (1.0f + __expf(-x)); }
__device__ __forceinline__ float tanhf_(float x) { return 2.0f / (1.0f + __expf(-2.0f * x)) - 1.0f; }

// Coherence-point h exchange via SUPPORTED intrinsics (round-5 inline asm crashed).
// Agent-scope RELAXED atomics bypass L1 + per-XCD L2 and operate at L3 — proven by
// round-4's relaxed poll observing cross-XCD counter updates while spinning.
__device__ __forceinline__ void st_h16(f16* p, f16 v) {
    unsigned short u;
    __builtin_memcpy(&u, &v, 2);
    __hip_atomic_store((unsigned short*)p, u, __ATOMIC_RELAXED, __HIP_MEMORY_SCOPE_AGENT);
}
__device__ __forceinline__ f16x8 ld_h128(const f16* p) {
    unsigned long long a = __hip_atomic_load((const unsigned long long*)p,       __ATOMIC_RELAXED, __HIP_MEMORY_SCOPE_AGENT);
    unsigned long long b = __hip_atomic_load((const unsigned long long*)(p + 4), __ATOMIC_RELAXED, __HIP_MEMORY_SCOPE_AGENT);
    union { unsigned long long q[2]; f16x8 v; } u;
    u.q[0] = a; u.q[1] = b;
    return u.v;
}

// in: R x C fp32 row-major -> out: C x R f16 row-major (i.e. transposed)
__global__ __launch_bounds__(256) void k_transpose_cvt(const float* __restrict__ in, f16* __restrict__ out, int R, int C) {
    int idx = blockIdx.x * 256 + threadIdx.x;
    if (idx < R * C) {
        int r = idx / C;
        int c = idx - r * C;
        out[(long)c * R + r] = (f16)in[idx];
    }
}

// Build weight frag-stream: for js slice (16 units), wave w (K-quarter), frag (mat, kk, nt=gate):
// chunk id = (((js*2+mat)*64 + w*16+kk*4+nt)*64 + lane), holds the f16x8 B-frag for that lane.
__global__ __launch_bounds__(256) void k_wfs(const f16* __restrict__ WiT, const f16* __restrict__ WhT,
                                             f16* __restrict__ Wfs) {
    int id = blockIdx.x * 256 + threadIdx.x;      // 262144 chunks
    int lane = id & 63;
    int f    = (id >> 6) & 63;                    // w*16 + kk*4 + nt
    int mat  = (id >> 12) & 1;
    int js   = id >> 13;                          // 0..31
    int nt = f & 3, kk = (f >> 2) & 3, w = f >> 4;
    const f16* WT = mat ? WhT : WiT;              // [2048][512] row-major (W^T)
    int col = nt * 512 + js * 16 + (lane & 15);   // gate nt, unit js*16 + l15
    int k   = (w * 4 + kk) * 32 + (lane >> 4) * 8;
    *(f16x8*)(Wfs + (long)id * 8) = *(const f16x8*)(WT + (long)col * 512 + k);
}

// ---------------- GEMM: C(MxN) = act(A(MxK) * BT(NxK)^T + bias), encoder use ----------------
template <int DO_GELU, int A_FP32>
__global__ __launch_bounds__(256) void k_gemm_bt(
    const void* __restrict__ Av, const f16* __restrict__ BT, const float* __restrict__ bias,
    f16* __restrict__ C, int M, int N, int K)
{
    __shared__ f16 As[128 * 32];
    __shared__ f16 Bs[128 * 32];
    const int tid = threadIdx.x;
    const int lane = tid & 63;
    const int wave = tid >> 6;
    const long m0 = (long)blockIdx.x * 128;
    const long n0 = (long)blockIdx.y * 128;
    const int wm = (wave >> 1) * 64, wn = (wave & 1) * 64;
    const int l15 = lane & 15, lq = lane >> 4;

    f32x4 acc[4][4] = {};

    for (int k0 = 0; k0 < K; k0 += 32) {
        __syncthreads();
#pragma unroll
        for (int i = 0; i < 2; i++) {
            int v = tid + 256 * i;
            int row = v >> 2, part = v & 3;
            if (A_FP32) {
                const float* A32 = (const float*)Av;
                const float* p = A32 + (m0 + row) * (long)K + k0 + part * 8;
                float4 v0 = *(const float4*)p;
                float4 v1 = *(const float4*)(p + 4);
                f16x8 o;
                o[0] = (f16)v0.x; o[1] = (f16)v0.y; o[2] = (f16)v0.z; o[3] = (f16)v0.w;
                o[4] = (f16)v1.x; o[5] = (f16)v1.y; o[6] = (f16)v1.z; o[7] = (f16)v1.w;
                *(f16x8*)&As[row * 32 + part * 8] = o;
            } else {
                const f16* A16 = (const f16*)Av;
                *(f16x8*)&As[row * 32 + part * 8] = *(const f16x8*)(A16 + (m0 + row) * (long)K + k0 + part * 8);
            }
            *(f16x8*)&Bs[row * 32 + part * 8] = *(const f16x8*)(BT + (n0 + row) * (long)K + k0 + part * 8);
        }
        __syncthreads();
        f16x8 af[4], bf[4];
#pragma unroll
        for (int i = 0; i < 4; i++) af[i] = *(const f16x8*)&As[(wm + i * 16 + l15) * 32 + lq * 8];
#pragma unroll
        for (int j = 0; j < 4; j++) bf[j] = *(const f16x8*)&Bs[(wn + j * 16 + l15) * 32 + lq * 8];
#pragma unroll
        for (int i = 0; i < 4; i++)
#pragma unroll
            for (int j = 0; j < 4; j++)
                acc[i][j] = __builtin_amdgcn_mfma_f32_16x16x32_f16(af[i], bf[j], acc[i][j], 0, 0, 0);
    }

#pragma unroll
    for (int i = 0; i < 4; i++) {
#pragma unroll
        for (int j = 0; j < 4; j++) {
#pragma unroll
            for (int r = 0; r < 4; r++) {
                long row = m0 + wm + i * 16 + lq * 4 + r;
                long col = n0 + wn + j * 16 + l15;
                float v = acc[i][j][r] + bias[col];
                if (DO_GELU) {
                    float u = 0.7978845608028654f * (v + 0.044715f * v * v * v);
                    v = 0.5f * v * (1.0f + tanhf(u));
                }
                C[row * (long)N + col] = (f16)v;
            }
        }
    }
}

// ---------------- persistent LSTM scan (64 steps per launch) ----------------
// grid 256 = js(32: 16 hidden units) x bg(8: 32 batch rows), bg = blockIdx & 7 (XCD-pin
// heuristic; correctness does not depend on it). h exchange: producer stores h via
// agent-relaxed atomic shorts (bypass -> L3), __syncthreads drains vmcnt(0), tid0 does a
// RELAXED agent fetch_add; consumer relaxed-polls, __syncthreads, loads h via agent-relaxed
// 8B atomic loads (bypass -> L3, always fresh). No release/acquire anywhere in the loop —
// round 4 showed the per-step wbl2/inv pair costs ~10 us/step; round 4's working relaxed
// poll proves agent-relaxed atomics bypass the per-XCD L2.
__global__ __launch_bounds__(256, 1) void k_scan(
    const f16* __restrict__ Wfs, const f16* __restrict__ feats,  // feats: chunk [64][256][512]
    f16* __restrict__ ys, float* __restrict__ cbuf,
    const float* __restrict__ b_lstm, int* __restrict__ ctr, int t0)
{
    __shared__ float zbuf[4][32][68];   // [wave][row b][col g*16+u]
    const int tid = threadIdx.x;
    const int lane = tid & 63, w = tid >> 6;
    const int l15 = lane & 15, lq = lane >> 4;
    const int bg = blockIdx.x & 7, js = blockIdx.x >> 3;
    const int B0 = bg * 32, j0 = js * 16;

    // weight fragments -> registers: [mat][kk][nt]
    f16x8 wfrag[2][4][4];
#pragma unroll
    for (int mat = 0; mat < 2; mat++)
#pragma unroll
        for (int kk = 0; kk < 4; kk++)
#pragma unroll
            for (int nt = 0; nt < 4; nt++)
                wfrag[mat][kk][nt] = *(const f16x8*)(Wfs +
                    ((long)((js * 2 + mat) * 64 + w * 16 + kk * 4 + nt) * 64 + lane) * 8);

    const int jj = tid & 15;
    const int b1 = tid >> 4, b2 = b1 + 16;
    float bias_v[4];
#pragma unroll
    for (int g = 0; g < 4; g++) bias_v[g] = b_lstm[g * 512 + j0 + jj];

    float c1, c2;
    if (t0 == 0) { c1 = 0.0f; c2 = 0.0f; }
    else {
        c1 = cbuf[(long)(B0 + b1) * 512 + j0 + jj];
        c2 = cbuf[(long)(B0 + b2) * 512 + j0 + jj];
    }

    for (int t = t0; t < t0 + 64; t++) {
        f32x4 acc[2][4] = {};

        // x-projection: independent of the barrier -> overlaps cluster stragglers
        const f16* fA = feats + ((long)(t - t0) * 256 + B0) * 512 + w * 128 + lq * 8;
#pragma unroll
        for (int kk = 0; kk < 4; kk++) {
            f16x8 xa0 = *(const f16x8*)(fA + (long)l15 * 512 + kk * 32);
            f16x8 xa1 = *(const f16x8*)(fA + (long)(16 + l15) * 512 + kk * 32);
#pragma unroll
            for (int nt = 0; nt < 4; nt++) {
                acc[0][nt] = __builtin_amdgcn_mfma_f32_16x16x32_f16(xa0, wfrag[0][kk][nt], acc[0][nt], 0, 0, 0);
                acc[1][nt] = __builtin_amdgcn_mfma_f32_16x16x32_f16(xa1, wfrag[0][kk][nt], acc[1][nt], 0, 0, 0);
            }
        }

        // wait for h(t-1) from the 32-block cluster (launch boundary covers t==t0).
        if (tid == 0 && t > t0) {
            const int ci = ((t - 1) * 8 + bg) * 16;   // 64B-padded counter
            while (__hip_atomic_load(&ctr[ci], __ATOMIC_RELAXED, __HIP_MEMORY_SCOPE_AGENT) < 32)
                __builtin_amdgcn_s_sleep(1);
        }
        __syncthreads();

        if (t > 0) {
            const f16* hA = ys + ((long)(t - 1) * 256 + B0) * 512 + w * 128 + lq * 8;
            f16x8 ha[2][4];
#pragma unroll
            for (int kk = 0; kk < 4; kk++) {
                ha[0][kk] = ld_h128(hA + (long)l15 * 512 + kk * 32);
                ha[1][kk] = ld_h128(hA + (long)(16 + l15) * 512 + kk * 32);
            }
#pragma unroll
            for (int kk = 0; kk < 4; kk++)
#pragma unroll
                for (int nt = 0; nt < 4; nt++) {
                    acc[0][nt] = __builtin_amdgcn_mfma_f32_16x16x32_f16(ha[0][kk], wfrag[1][kk][nt], acc[0][nt], 0, 0, 0);
                    acc[1][nt] = __builtin_amdgcn_mfma_f32_16x16x32_f16(ha[1][kk], wfrag[1][kk][nt], acc[1][nt], 0, 0, 0);
                }
        }

        // K-partials -> LDS (C/D layout: col=lane&15, row=lq*4+r)
#pragma unroll
        for (int mt = 0; mt < 2; mt++)
#pragma unroll
            for (int nt = 0; nt < 4; nt++)
#pragma unroll
                for (int r = 0; r < 4; r++)
                    zbuf[w][mt * 16 + lq * 4 + r][nt * 16 + l15] = acc[mt][nt][r];
        __syncthreads();

        // gate phase: each thread owns (b1,jj) and (b2,jj); h published via bypass stores
        {
            float zs1[4], zs2[4];
#pragma unroll
            for (int g = 0; g < 4; g++) {
                float a1 = bias_v[g], a2 = bias_v[g];
#pragma unroll
                for (int ww = 0; ww < 4; ww++) {
                    a1 += zbuf[ww][b1][g * 16 + jj];
                    a2 += zbuf[ww][b2][g * 16 + jj];
                }
                zs1[g] = a1; zs2[g] = a2;
            }
            c1 = sigmoidf_(zs1[1]) * c1 + sigmoidf_(zs1[0]) * tanhf_(zs1[2]);
            float h1 = sigmoidf_(zs1[3]) * tanhf_(c1);
            c2 = sigmoidf_(zs2[1]) * c2 + sigmoidf_(zs2[0]) * tanhf_(zs2[2]);
            float h2 = sigmoidf_(zs2[3]) * tanhf_(c2);
            st_h16(ys + (long)t * 131072 + (long)(B0 + b1) * 512 + j0 + jj, (f16)h1);
            st_h16(ys + (long)t * 131072 + (long)(B0 + b2) * 512 + j0 + jj, (f16)h2);
        }
        __syncthreads();    // vmcnt(0): all waves' bypass stores ACKed at L3; zbuf reads done

        if (tid == 0) {
            // RELAXED add: this block's h(t) is already at the coherence point
            __hip_atomic_fetch_add(&ctr[(t * 8 + bg) * 16], 1, __ATOMIC_RELAXED, __HIP_MEMORY_SCOPE_AGENT);
        }
    }

    cbuf[(long)(B0 + b1) * 512 + j0 + jj] = c1;
    cbuf[(long)(B0 + b2) * 512 + j0 + jj] = c2;
}

// ---------------- heads: mu, sigma, value ----------------
__global__ __launch_bounds__(256) void k_heads(
    const f16* __restrict__ ys, const float* __restrict__ Wmu, const float* __restrict__ bmu,
    const float* __restrict__ logstd, const float* __restrict__ Wv, const float* __restrict__ bv,
    float* __restrict__ mu, float* __restrict__ sigma, float* __restrict__ value)
{
    __shared__ f16 hsm[8][512];
    const int tid = threadIdx.x;
    const long base_row = (long)blockIdx.x * 8;
    for (int v = tid; v < 512; v += 256) {
        int row = v >> 6, part = v & 63;
        *(f16x8*)&hsm[row][part * 8] = *(const f16x8*)(ys + (base_row + row) * 512 + part * 8);
    }
    __syncthreads();
    const int n = tid & 31, rl = tid >> 5;
    float accm = 0.0f, accv = 0.0f;
    for (int k = 0; k < 512; k++) accm += (float)hsm[rl][k] * Wmu[k * 32 + n];
    for (int kk = 0; kk < 16; kk++) {
        int k = n + kk * 32;
        accv += (float)hsm[rl][k] * Wv[k];
    }
    for (int off = 16; off; off >>= 1) accv += __shfl_down(accv, off, 32);
    long r = base_row + rl;
    mu[r * 32 + n] = accm + bmu[n];
    sigma[r * 32 + n] = expf(logstd[n]);
    if (n == 0) value[r] = accv + bv[0];
}

// ---------------- launcher ----------------
// ws layout (bytes):
//   ys     @ 0          134217728  (131072 x 512 f16)
//   fchunk @ 134217728  16777216   (16384 x 512 f16)
//   WiT    @ 150994944  2097152
//   WhT    @ 153092096  2097152
//   WencT  @ 155189248  262144
//   Wfs    @ 155451392  4194304    (frag-stream Wi+Wh)
//   cbuf   @ 159645696  524288     (256 x 512 f32)
//   ctr    @ 160169984  262144     (512 x 8 counters, 64B padded)
//   total ~160.4 MB (known-good <= 213 MB)

extern "C" void kernel_launch(void* const* d_in, const int* in_sizes, int n_in,
                              void* d_out, int out_size, void* d_ws, size_t ws_size,
                              hipStream_t stream)
{
    const float* x      = (const float*)d_in[0];
    const float* W_enc  = (const float*)d_in[1];
    const float* b_enc  = (const float*)d_in[2];
    const float* W_i    = (const float*)d_in[3];
    const float* W_h    = (const float*)d_in[4];
    const float* b_lstm = (const float*)d_in[5];
    const float* W_mu   = (const float*)d_in[6];
    const float* b_mu   = (const float*)d_in[7];
    const float* log_std= (const float*)d_in[8];
    const float* W_v    = (const float*)d_in[9];
    const float* b_v    = (const float*)d_in[10];

    char* ws = (char*)d_ws;
    f16*   ys    = (f16*)(ws);
    f16*   fchunk= (f16*)(ws + 134217728);
    f16*   WiT   = (f16*)(ws + 150994944);
    f16*   WhT   = (f16*)(ws + 153092096);
    f16*   WencT = (f16*)(ws + 155189248);
    f16*   Wfs   = (f16*)(ws + 155451392);
    float* cbuf  = (float*)(ws + 159645696);
    int*   ctr   = (int*)(ws + 160169984);

    float* mu    = (float*)d_out;
    float* sigma = mu + 4194304;
    float* value = mu + 8388608;

    hipMemsetAsync(ctr, 0, 262144, stream);
    hipLaunchKernelGGL(k_transpose_cvt, dim3(512), dim3(256), 0, stream, W_enc, WencT, 256, 512);
    hipLaunchKernelGGL(k_transpose_cvt, dim3(4096), dim3(256), 0, stream, W_i, WiT, 512, 2048);
    hipLaunchKernelGGL(k_transpose_cvt, dim3(4096), dim3(256), 0, stream, W_h, WhT, 512, 2048);
    hipLaunchKernelGGL(k_wfs, dim3(1024), dim3(256), 0, stream, WiT, WhT, Wfs);

    for (int t0 = 0; t0 < 512; t0 += 64) {
        // feats_chunk = gelu(x[t0:t0+64] @ W_enc + b_enc): M=16384, N=512, K=256 (A fp32)
        hipLaunchKernelGGL((k_gemm_bt<1, 1>), dim3(128, 4), dim3(256), 0, stream,
                           (const void*)(x + (long)t0 * 256 * 256), WencT, b_enc, fchunk,
                           16384, 512, 256);
        const f16* wfs_c = Wfs; const f16* f_c = fchunk;
        void* args[] = { (void*)&wfs_c, (void*)&f_c, (void*)&ys, (void*)&cbuf,
                         (void*)&b_lstm, (void*)&ctr, (void*)&t0 };
        hipLaunchCooperativeKernel((const void*)k_scan, dim3(256), dim3(256), args, 0, stream);
    }

    hipLaunchKernelGGL(k_heads, dim3(16384), dim3(256), 0, stream,
                       ys, W_mu, b_mu, log_std, W_v, b_v, mu, sigma, value);
}

// Round 7
// 3161.159 us; speedup vs baseline: 4.3004x; 1.1045x over previous
//
#include <hip/hip_runtime.h>
#include <hip/hip_bf16.h>
#include <hip/hip_fp16.h>

typedef _Float16 f16;
typedef __attribute__((ext_vector_type(8))) _Float16 f16x8;
typedef __attribute__((ext_vector_type(4))) float f32x4;

__device__ __forceinline__ float sigmoidf_(float x) { return 1.0f / (1.0f + __expf(-x)); }
__device__ __forceinline__ float tanhf_(float x) { return 2.0f / (1.0f + __expf(-2.0f * x)) - 1.0f; }

// Coherence-point h exchange via supported intrinsics.
// Agent-scope RELAXED atomics bypass L1 + per-XCD L2 and operate at L3 — proven by
// round-4/6 behavior (relaxed poll sees cross-XCD updates; round 6 passed with this path).
__device__ __forceinline__ void st_h16(f16* p, f16 v) {
    unsigned short u;
    __builtin_memcpy(&u, &v, 2);
    __hip_atomic_store((unsigned short*)p, u, __ATOMIC_RELAXED, __HIP_MEMORY_SCOPE_AGENT);
}
__device__ __forceinline__ f16x8 ld_h128(const f16* p) {
    unsigned long long a = __hip_atomic_load((const unsigned long long*)p,       __ATOMIC_RELAXED, __HIP_MEMORY_SCOPE_AGENT);
    unsigned long long b = __hip_atomic_load((const unsigned long long*)(p + 4), __ATOMIC_RELAXED, __HIP_MEMORY_SCOPE_AGENT);
    union { unsigned long long q[2]; f16x8 v; } u;
    u.q[0] = a; u.q[1] = b;
    return u.v;
}

// in: R x C fp32 row-major -> out: C x R f16 row-major (i.e. transposed)
__global__ __launch_bounds__(256) void k_transpose_cvt(const float* __restrict__ in, f16* __restrict__ out, int R, int C) {
    int idx = blockIdx.x * 256 + threadIdx.x;
    if (idx < R * C) {
        int r = idx / C;
        int c = idx - r * C;
        out[(long)c * R + r] = (f16)in[idx];
    }
}

// Build weight frag-stream: for js slice (16 units), wave w (K-quarter), frag (mat, kk, nt=gate):
// chunk id = (((js*2+mat)*64 + w*16+kk*4+nt)*64 + lane), holds the f16x8 B-frag for that lane.
__global__ __launch_bounds__(256) void k_wfs(const f16* __restrict__ WiT, const f16* __restrict__ WhT,
                                             f16* __restrict__ Wfs) {
    int id = blockIdx.x * 256 + threadIdx.x;      // 262144 chunks
    int lane = id & 63;
    int f    = (id >> 6) & 63;                    // w*16 + kk*4 + nt
    int mat  = (id >> 12) & 1;
    int js   = id >> 13;                          // 0..31
    int nt = f & 3, kk = (f >> 2) & 3, w = f >> 4;
    const f16* WT = mat ? WhT : WiT;              // [2048][512] row-major (W^T)
    int col = nt * 512 + js * 16 + (lane & 15);   // gate nt, unit js*16 + l15
    int k   = (w * 4 + kk) * 32 + (lane >> 4) * 8;
    *(f16x8*)(Wfs + (long)id * 8) = *(const f16x8*)(WT + (long)col * 512 + k);
}

// ---------------- GEMM: C(MxN) = act(A(MxK) * BT(NxK)^T + bias), encoder use ----------------
template <int DO_GELU, int A_FP32>
__global__ __launch_bounds__(256) void k_gemm_bt(
    const void* __restrict__ Av, const f16* __restrict__ BT, const float* __restrict__ bias,
    f16* __restrict__ C, int M, int N, int K)
{
    __shared__ f16 As[128 * 32];
    __shared__ f16 Bs[128 * 32];
    const int tid = threadIdx.x;
    const int lane = tid & 63;
    const int wave = tid >> 6;
    const long m0 = (long)blockIdx.x * 128;
    const long n0 = (long)blockIdx.y * 128;
    const int wm = (wave >> 1) * 64, wn = (wave & 1) * 64;
    const int l15 = lane & 15, lq = lane >> 4;

    f32x4 acc[4][4] = {};

    for (int k0 = 0; k0 < K; k0 += 32) {
        __syncthreads();
#pragma unroll
        for (int i = 0; i < 2; i++) {
            int v = tid + 256 * i;
            int row = v >> 2, part = v & 3;
            if (A_FP32) {
                const float* A32 = (const float*)Av;
                const float* p = A32 + (m0 + row) * (long)K + k0 + part * 8;
                float4 v0 = *(const float4*)p;
                float4 v1 = *(const float4*)(p + 4);
                f16x8 o;
                o[0] = (f16)v0.x; o[1] = (f16)v0.y; o[2] = (f16)v0.z; o[3] = (f16)v0.w;
                o[4] = (f16)v1.x; o[5] = (f16)v1.y; o[6] = (f16)v1.z; o[7] = (f16)v1.w;
                *(f16x8*)&As[row * 32 + part * 8] = o;
            } else {
                const f16* A16 = (const f16*)Av;
                *(f16x8*)&As[row * 32 + part * 8] = *(const f16x8*)(A16 + (m0 + row) * (long)K + k0 + part * 8);
            }
            *(f16x8*)&Bs[row * 32 + part * 8] = *(const f16x8*)(BT + (n0 + row) * (long)K + k0 + part * 8);
        }
        __syncthreads();
        f16x8 af[4], bf[4];
#pragma unroll
        for (int i = 0; i < 4; i++) af[i] = *(const f16x8*)&As[(wm + i * 16 + l15) * 32 + lq * 8];
#pragma unroll
        for (int j = 0; j < 4; j++) bf[j] = *(const f16x8*)&Bs[(wn + j * 16 + l15) * 32 + lq * 8];
#pragma unroll
        for (int i = 0; i < 4; i++)
#pragma unroll
            for (int j = 0; j < 4; j++)
                acc[i][j] = __builtin_amdgcn_mfma_f32_16x16x32_f16(af[i], bf[j], acc[i][j], 0, 0, 0);
    }

#pragma unroll
    for (int i = 0; i < 4; i++) {
#pragma unroll
        for (int j = 0; j < 4; j++) {
#pragma unroll
            for (int r = 0; r < 4; r++) {
                long row = m0 + wm + i * 16 + lq * 4 + r;
                long col = n0 + wn + j * 16 + l15;
                float v = acc[i][j][r] + bias[col];
                if (DO_GELU) {
                    float u = 0.7978845608028654f * (v + 0.044715f * v * v * v);
                    v = 0.5f * v * (1.0f + tanhf(u));
                }
                C[row * (long)N + col] = (f16)v;
            }
        }
    }
}

// ---------------- persistent LSTM scan (256 steps per launch) ----------------
// grid 256 = js(32: 16 hidden units) x bg(8: 32 batch rows), bg = blockIdx & 7 (XCD-pin
// heuristic; correctness does not depend on it). h exchange via agent-relaxed bypass
// atomics (L3 coherence point). Sync protocol (round-7): per-producer-BLOCK flags
// (64B padded, tid0 stores t+1) — no atomic RMW contention (round 6: 32 fetch_adds to one
// line serialized at L3); consumer WAVES poll only their 8 producer blocks (their
// K-quarter) via __all over lanes, then proceed without a block barrier.
__global__ __launch_bounds__(256, 1) void k_scan(
    const f16* __restrict__ Wfs, const f16* __restrict__ feats,  // feats: chunk [CH][256][512]
    f16* __restrict__ ys, float* __restrict__ cbuf,
    const float* __restrict__ b_lstm, int* __restrict__ flags, int t0)
{
    __shared__ float zbuf[4][32][68];   // [wave][row b][col g*16+u]
    const int tid = threadIdx.x;
    const int lane = tid & 63, w = tid >> 6;
    const int l15 = lane & 15, lq = lane >> 4;
    const int bg = blockIdx.x & 7, js = blockIdx.x >> 3;
    const int B0 = bg * 32, j0 = js * 16;

    // weight fragments -> registers: [mat][kk][nt]
    f16x8 wfrag[2][4][4];
#pragma unroll
    for (int mat = 0; mat < 2; mat++)
#pragma unroll
        for (int kk = 0; kk < 4; kk++)
#pragma unroll
            for (int nt = 0; nt < 4; nt++)
                wfrag[mat][kk][nt] = *(const f16x8*)(Wfs +
                    ((long)((js * 2 + mat) * 64 + w * 16 + kk * 4 + nt) * 64 + lane) * 8);

    const int jj = tid & 15;
    const int b1 = tid >> 4, b2 = b1 + 16;
    float bias_v[4];
#pragma unroll
    for (int g = 0; g < 4; g++) bias_v[g] = b_lstm[g * 512 + j0 + jj];

    float c1, c2;
    if (t0 == 0) { c1 = 0.0f; c2 = 0.0f; }
    else {
        c1 = cbuf[(long)(B0 + b1) * 512 + j0 + jj];
        c2 = cbuf[(long)(B0 + b2) * 512 + j0 + jj];
    }

    // this wave's 8 producer blocks (covering units w*128 .. w*128+127)
    int* my_flag = &flags[((bg * 32 + w * 8 + (lane & 7)) * 16)];

    for (int t = t0; t < t0 + 256; t++) {
        f32x4 acc[2][4] = {};

        // x-projection: independent of the barrier -> overlaps cluster stragglers
        const f16* fA = feats + ((long)(t - t0) * 256 + B0) * 512 + w * 128 + lq * 8;
#pragma unroll
        for (int kk = 0; kk < 4; kk++) {
            f16x8 xa0 = *(const f16x8*)(fA + (long)l15 * 512 + kk * 32);
            f16x8 xa1 = *(const f16x8*)(fA + (long)(16 + l15) * 512 + kk * 32);
#pragma unroll
            for (int nt = 0; nt < 4; nt++) {
                acc[0][nt] = __builtin_amdgcn_mfma_f32_16x16x32_f16(xa0, wfrag[0][kk][nt], acc[0][nt], 0, 0, 0);
                acc[1][nt] = __builtin_amdgcn_mfma_f32_16x16x32_f16(xa1, wfrag[0][kk][nt], acc[1][nt], 0, 0, 0);
            }
        }

        // wave-local wait for this wave's 8 producer blocks (launch boundary covers t==t0)
        if (t > t0) {
            while (!__all(__hip_atomic_load(my_flag, __ATOMIC_RELAXED, __HIP_MEMORY_SCOPE_AGENT) >= t))
                __builtin_amdgcn_s_sleep(1);
        }

        if (t > 0) {
            const f16* hA = ys + ((long)(t - 1) * 256 + B0) * 512 + w * 128 + lq * 8;
            f16x8 ha[2][4];
#pragma unroll
            for (int kk = 0; kk < 4; kk++) {
                ha[0][kk] = ld_h128(hA + (long)l15 * 512 + kk * 32);
                ha[1][kk] = ld_h128(hA + (long)(16 + l15) * 512 + kk * 32);
            }
#pragma unroll
            for (int kk = 0; kk < 4; kk++)
#pragma unroll
                for (int nt = 0; nt < 4; nt++) {
                    acc[0][nt] = __builtin_amdgcn_mfma_f32_16x16x32_f16(ha[0][kk], wfrag[1][kk][nt], acc[0][nt], 0, 0, 0);
                    acc[1][nt] = __builtin_amdgcn_mfma_f32_16x16x32_f16(ha[1][kk], wfrag[1][kk][nt], acc[1][nt], 0, 0, 0);
                }
        }

        // K-partials -> LDS (C/D layout: col=lane&15, row=lq*4+r)
#pragma unroll
        for (int mt = 0; mt < 2; mt++)
#pragma unroll
            for (int nt = 0; nt < 4; nt++)
#pragma unroll
                for (int r = 0; r < 4; r++)
                    zbuf[w][mt * 16 + lq * 4 + r][nt * 16 + l15] = acc[mt][nt][r];
        __syncthreads();

        // gate phase: each thread owns (b1,jj) and (b2,jj); h published via bypass stores
        {
            float zs1[4], zs2[4];
#pragma unroll
            for (int g = 0; g < 4; g++) {
                float a1 = bias_v[g], a2 = bias_v[g];
#pragma unroll
                for (int ww = 0; ww < 4; ww++) {
                    a1 += zbuf[ww][b1][g * 16 + jj];
                    a2 += zbuf[ww][b2][g * 16 + jj];
                }
                zs1[g] = a1; zs2[g] = a2;
            }
            c1 = sigmoidf_(zs1[1]) * c1 + sigmoidf_(zs1[0]) * tanhf_(zs1[2]);
            float h1 = sigmoidf_(zs1[3]) * tanhf_(c1);
            c2 = sigmoidf_(zs2[1]) * c2 + sigmoidf_(zs2[0]) * tanhf_(zs2[2]);
            float h2 = sigmoidf_(zs2[3]) * tanhf_(c2);
            st_h16(ys + (long)t * 131072 + (long)(B0 + b1) * 512 + j0 + jj, (f16)h1);
            st_h16(ys + (long)t * 131072 + (long)(B0 + b2) * 512 + j0 + jj, (f16)h2);
        }
        __syncthreads();    // vmcnt(0) drained per wave before barrier => all h stores ACKed at L3

        if (tid == 0) {
            // publish: this block's h(t) is visible; flag is monotone (t+1)
            __hip_atomic_store(&flags[(bg * 32 + js) * 16], t + 1, __ATOMIC_RELAXED, __HIP_MEMORY_SCOPE_AGENT);
        }
    }

    cbuf[(long)(B0 + b1) * 512 + j0 + jj] = c1;
    cbuf[(long)(B0 + b2) * 512 + j0 + jj] = c2;
}

// ---------------- heads: mu, sigma, value ----------------
__global__ __launch_bounds__(256) void k_heads(
    const f16* __restrict__ ys, const float* __restrict__ Wmu, const float* __restrict__ bmu,
    const float* __restrict__ logstd, const float* __restrict__ Wv, const float* __restrict__ bv,
    float* __restrict__ mu, float* __restrict__ sigma, float* __restrict__ value)
{
    __shared__ f16 hsm[8][512];
    const int tid = threadIdx.x;
    const long base_row = (long)blockIdx.x * 8;
    for (int v = tid; v < 512; v += 256) {
        int row = v >> 6, part = v & 63;
        *(f16x8*)&hsm[row][part * 8] = *(const f16x8*)(ys + (base_row + row) * 512 + part * 8);
    }
    __syncthreads();
    const int n = tid & 31, rl = tid >> 5;
    float accm = 0.0f, accv = 0.0f;
    for (int k = 0; k < 512; k++) accm += (float)hsm[rl][k] * Wmu[k * 32 + n];
    for (int kk = 0; kk < 16; kk++) {
        int k = n + kk * 32;
        accv += (float)hsm[rl][k] * Wv[k];
    }
    for (int off = 16; off; off >>= 1) accv += __shfl_down(accv, off, 32);
    long r = base_row + rl;
    mu[r * 32 + n] = accm + bmu[n];
    sigma[r * 32 + n] = expf(logstd[n]);
    if (n == 0) value[r] = accv + bv[0];
}

// ---------------- launcher ----------------
// ws layout (bytes):
//   ys     @ 0          134217728  (131072 x 512 f16)
//   fchunk @ 134217728  67108864   (256*256 x 512 f16)
//   WiT    @ 201326592  2097152
//   WhT    @ 203423744  2097152
//   WencT  @ 205520896  262144
//   Wfs    @ 205783040  4194304    (frag-stream Wi+Wh)
//   cbuf   @ 209977344  524288     (256 x 512 f32)
//   flags  @ 210501632  16384      (256 per-block flags, 64B padded)
//   total ~210.5 MB (known-good <= 213 MB)

extern "C" void kernel_launch(void* const* d_in, const int* in_sizes, int n_in,
                              void* d_out, int out_size, void* d_ws, size_t ws_size,
                              hipStream_t stream)
{
    const float* x      = (const float*)d_in[0];
    const float* W_enc  = (const float*)d_in[1];
    const float* b_enc  = (const float*)d_in[2];
    const float* W_i    = (const float*)d_in[3];
    const float* W_h    = (const float*)d_in[4];
    const float* b_lstm = (const float*)d_in[5];
    const float* W_mu   = (const float*)d_in[6];
    const float* b_mu   = (const float*)d_in[7];
    const float* log_std= (const float*)d_in[8];
    const float* W_v    = (const float*)d_in[9];
    const float* b_v    = (const float*)d_in[10];

    char* ws = (char*)d_ws;
    f16*   ys    = (f16*)(ws);
    f16*   fchunk= (f16*)(ws + 134217728);
    f16*   WiT   = (f16*)(ws + 201326592);
    f16*   WhT   = (f16*)(ws + 203423744);
    f16*   WencT = (f16*)(ws + 205520896);
    f16*   Wfs   = (f16*)(ws + 205783040);
    float* cbuf  = (float*)(ws + 209977344);
    int*   flags = (int*)(ws + 210501632);

    float* mu    = (float*)d_out;
    float* sigma = mu + 4194304;
    float* value = mu + 8388608;

    hipMemsetAsync(flags, 0, 16384, stream);
    hipLaunchKernelGGL(k_transpose_cvt, dim3(512), dim3(256), 0, stream, W_enc, WencT, 256, 512);
    hipLaunchKernelGGL(k_transpose_cvt, dim3(4096), dim3(256), 0, stream, W_i, WiT, 512, 2048);
    hipLaunchKernelGGL(k_transpose_cvt, dim3(4096), dim3(256), 0, stream, W_h, WhT, 512, 2048);
    hipLaunchKernelGGL(k_wfs, dim3(1024), dim3(256), 0, stream, WiT, WhT, Wfs);

    for (int t0 = 0; t0 < 512; t0 += 256) {
        // feats_chunk = gelu(x[t0:t0+256] @ W_enc + b_enc): M=65536, N=512, K=256 (A fp32)
        hipLaunchKernelGGL((k_gemm_bt<1, 1>), dim3(512, 4), dim3(256), 0, stream,
                           (const void*)(x + (long)t0 * 256 * 256), WencT, b_enc, fchunk,
                           65536, 512, 256);
        const f16* wfs_c = Wfs; const f16* f_c = fchunk;
        void* args[] = { (void*)&wfs_c, (void*)&f_c, (void*)&ys, (void*)&cbuf,
                         (void*)&b_lstm, (void*)&flags, (void*)&t0 };
        hipLaunchCooperativeKernel((const void*)k_scan, dim3(256), dim3(256), args, 0, stream);
    }

    hipLaunchKernelGGL(k_heads, dim3(16384), dim3(256), 0, stream,
                       ys, W_mu, b_mu, log_std, W_v, b_v, mu, sigma, value);
}